// Round 1
// baseline (2362.509 us; speedup 1.0000x reference)
//
#include <hip/hip_runtime.h>
#include <hip/hip_bf16.h>

#define B_ 16
#define N_ 4096
#define D_ 1024
#define K_ 1024
#define M_ 3072

// ---------------------------------------------------------------------------
// Kernel 1: per-batch top-K selection (JAX top_k tie semantics: equal score ->
// lower index wins), kept list in ascending original-index order, dropped list
// ascending. One block per batch; bitonic sort of 64-bit keys in LDS.
// key = (monotone(score_bits) << 32) | (N-1-i)  -> unique keys, stable ties.
// ---------------------------------------------------------------------------
__global__ __launch_bounds__(1024)
void topk_kernel(const float* __restrict__ scores,
                 float* __restrict__ out_idx_f, float* __restrict__ out_sc,
                 int* __restrict__ kept_idx, int* __restrict__ dropped_idx,
                 float* __restrict__ kept_sc,
                 unsigned long long* __restrict__ assign_key)
{
    const int b = blockIdx.x;
    const int tid = threadIdx.x;
    __shared__ unsigned long long keys[N_];
    __shared__ unsigned wsum[16];

    // re-init assignment keys every launch (ws is poisoned between launches)
    for (int m = tid; m < M_; m += 1024) assign_key[b * M_ + m] = 0ull;

    for (int i = tid; i < N_; i += 1024) {
        float s = scores[b * N_ + i];
        unsigned sb = __float_as_uint(s);
        sb = (sb & 0x80000000u) ? ~sb : (sb | 0x80000000u);
        keys[i] = ((unsigned long long)sb << 32) | (unsigned)(N_ - 1 - i);
    }
    __syncthreads();

    // bitonic sort ascending
    for (unsigned k = 2; k <= (unsigned)N_; k <<= 1) {
        for (unsigned j = k >> 1; j > 0; j >>= 1) {
            for (unsigned i = tid; i < (unsigned)N_; i += 1024) {
                unsigned ixj = i ^ j;
                if (ixj > i) {
                    unsigned long long a = keys[i], c = keys[ixj];
                    bool up = ((i & k) == 0);
                    if ((a > c) == up) { keys[i] = c; keys[ixj] = a; }
                }
            }
            __syncthreads();
        }
    }

    const unsigned long long thr = keys[N_ - K_];   // K-th largest key
    const int lane = tid & 63, w = tid >> 6;
    unsigned carry = 0;

    for (int r = 0; r < 4; ++r) {
        const int e = r * 1024 + tid;
        const float s = scores[b * N_ + e];
        unsigned sb = __float_as_uint(s);
        sb = (sb & 0x80000000u) ? ~sb : (sb | 0x80000000u);
        const unsigned long long key =
            ((unsigned long long)sb << 32) | (unsigned)(N_ - 1 - e);
        const bool kept = (key >= thr);

        const unsigned long long mb = __ballot(kept);
        const unsigned lanePre = (unsigned)__popcll(mb & ((1ull << lane) - 1ull));
        if (lane == 0) wsum[w] = (unsigned)__popcll(mb);
        __syncthreads();
        unsigned waveExcl = 0, roundTot = 0;
        for (int i = 0; i < 16; ++i) {
            unsigned v = wsum[i];
            if (i < w) waveExcl += v;
            roundTot += v;
        }
        const unsigned kpos = carry + waveExcl + lanePre;
        if (kept) {
            out_idx_f[b * K_ + kpos] = (float)e;
            out_sc  [b * K_ + kpos] = s;
            kept_idx[b * K_ + kpos] = e;
            kept_sc [b * K_ + kpos] = fmaxf(s, 0.0f);
        } else {
            const unsigned q = (unsigned)e - kpos;   // dropped position
            dropped_idx[b * M_ + q] = e;
        }
        carry += roundTot;
        __syncthreads();
    }
}

// ---------------------------------------------------------------------------
// Kernel 2: per kept token -- inverse L2 norm, init out = kept * relu(score),
// zero score accumulator. One wave per kept token.
// ---------------------------------------------------------------------------
__global__ __launch_bounds__(256)
void prep_kernel(const float* __restrict__ tokens,
                 const int* __restrict__ kept_idx, const float* __restrict__ kept_sc,
                 float* __restrict__ inv_knorm, float* __restrict__ score_accum,
                 float* __restrict__ out_tok)
{
    const int w = threadIdx.x >> 6, lane = threadIdx.x & 63;
    const int g = blockIdx.x * 4 + w;          // [0, B*K)
    const int b = g >> 10;                     // K_ = 1024
    const int idx = kept_idx[g];
    const float* src = tokens + ((size_t)b * N_ + idx) * D_;

    float4 v[4];
    float ss = 0.0f;
#pragma unroll
    for (int j = 0; j < 4; ++j) {
        v[j] = *(const float4*)(src + (lane + j * 64) * 4);
        ss += v[j].x * v[j].x + v[j].y * v[j].y + v[j].z * v[j].z + v[j].w * v[j].w;
    }
#pragma unroll
    for (int sh = 1; sh < 64; sh <<= 1) ss += __shfl_xor(ss, sh, 64);

    const float inv = 1.0f / fmaxf(sqrtf(ss), 1e-12f);
    const float ksc = kept_sc[g];
    float* dst = out_tok + (size_t)g * D_;
#pragma unroll
    for (int j = 0; j < 4; ++j) {
        float4 o;
        o.x = v[j].x * ksc; o.y = v[j].y * ksc; o.z = v[j].z * ksc; o.w = v[j].w * ksc;
        *(float4*)(dst + (lane + j * 64) * 4) = o;
    }
    if (lane == 0) { inv_knorm[g] = inv; score_accum[g] = 0.0f; }
}

// ---------------------------------------------------------------------------
// Kernel 3: sim = dropped . kept^T (fp32), fused row-argmax over K via packed
// u64 atomicMax: key = (monotone(simbits)<<32) | (0xFFFFFFFF - k)  -> max sim,
// tie -> min k (matches jnp.argmax first-occurrence).
// inv_d is a positive per-row constant -> argmax-invariant, omitted.
// Tile 64x64, 256 threads, each thread 4x4.
// ---------------------------------------------------------------------------
#define TBM 64
#define TBK 64
#define TBD 16
#define LDA 68   // padded LDS stride (16B-aligned float4 rows, conflict-free)

__global__ __launch_bounds__(256)
void sim_argmax_kernel(const float* __restrict__ tokens,
                       const int* __restrict__ kept_idx,
                       const int* __restrict__ dropped_idx,
                       const float* __restrict__ inv_knorm,
                       unsigned long long* __restrict__ assign_key)
{
    const int b = blockIdx.z, mt = blockIdx.y, kt = blockIdx.x;
    const int tid = threadIdx.x;
    __shared__ float As[TBD * LDA], Bs[TBD * LDA];

    const int srow = tid >> 2, sc4 = tid & 3;         // stage: 64 rows x 4 float4
    const int aTok = dropped_idx[b * M_ + mt * TBM + srow];
    const int bTok = kept_idx  [b * K_ + kt * TBK + srow];
    const float* aSrc = tokens + ((size_t)b * N_ + aTok) * D_ + sc4 * 4;
    const float* bSrc = tokens + ((size_t)b * N_ + bTok) * D_ + sc4 * 4;

    const int tx = tid & 15, ty = tid >> 4;
    float acc[4][4] = {{0.f}};

    for (int d0 = 0; d0 < D_; d0 += TBD) {
        const float4 av = *(const float4*)(aSrc + d0);
        const float4 bv = *(const float4*)(bSrc + d0);
        __syncthreads();
        As[(sc4 * 4 + 0) * LDA + srow] = av.x;
        As[(sc4 * 4 + 1) * LDA + srow] = av.y;
        As[(sc4 * 4 + 2) * LDA + srow] = av.z;
        As[(sc4 * 4 + 3) * LDA + srow] = av.w;
        Bs[(sc4 * 4 + 0) * LDA + srow] = bv.x;
        Bs[(sc4 * 4 + 1) * LDA + srow] = bv.y;
        Bs[(sc4 * 4 + 2) * LDA + srow] = bv.z;
        Bs[(sc4 * 4 + 3) * LDA + srow] = bv.w;
        __syncthreads();
#pragma unroll
        for (int d = 0; d < TBD; ++d) {
            const float4 a4 = *(const float4*)&As[d * LDA + ty * 4];
            const float4 b4 = *(const float4*)&Bs[d * LDA + tx * 4];
            acc[0][0] += a4.x * b4.x; acc[0][1] += a4.x * b4.y;
            acc[0][2] += a4.x * b4.z; acc[0][3] += a4.x * b4.w;
            acc[1][0] += a4.y * b4.x; acc[1][1] += a4.y * b4.y;
            acc[1][2] += a4.y * b4.z; acc[1][3] += a4.y * b4.w;
            acc[2][0] += a4.z * b4.x; acc[2][1] += a4.z * b4.y;
            acc[2][2] += a4.z * b4.z; acc[2][3] += a4.z * b4.w;
            acc[3][0] += a4.w * b4.x; acc[3][1] += a4.w * b4.y;
            acc[3][2] += a4.w * b4.z; acc[3][3] += a4.w * b4.w;
        }
    }

    float invk[4];
#pragma unroll
    for (int j = 0; j < 4; ++j) invk[j] = inv_knorm[b * K_ + kt * TBK + tx * 4 + j];

#pragma unroll
    for (int i = 0; i < 4; ++i) {
        float bestv = acc[i][0] * invk[0];
        int bestk = kt * TBK + tx * 4;
#pragma unroll
        for (int j = 1; j < 4; ++j) {
            const float v = acc[i][j] * invk[j];
            if (v > bestv) { bestv = v; bestk = kt * TBK + tx * 4 + j; }
        }
        unsigned u = __float_as_uint(bestv);
        u = (u & 0x80000000u) ? ~u : (u | 0x80000000u);
        unsigned long long key = ((unsigned long long)u << 32)
                               | (unsigned long long)(0xFFFFFFFFu - (unsigned)bestk);
        // reduce across the 16 lanes (same ty group) holding this row's columns
#pragma unroll
        for (int sh = 1; sh < 16; sh <<= 1) {
            unsigned lo = (unsigned)key, hi = (unsigned)(key >> 32);
            lo = __shfl_xor(lo, sh, 64);
            hi = __shfl_xor(hi, sh, 64);
            const unsigned long long o = ((unsigned long long)hi << 32) | lo;
            if (o > key) key = o;
        }
        if (tx == 0) {
            const int mg = mt * TBM + ty * 4 + i;
            atomicMax(&assign_key[b * M_ + mg], key);
        }
    }
}

// ---------------------------------------------------------------------------
// Kernel 4: scatter weighted dropped tokens into assigned kept rows.
// One block per dropped token.
// ---------------------------------------------------------------------------
__global__ __launch_bounds__(256)
void scatter_kernel(const float* __restrict__ tokens, const float* __restrict__ scores,
                    const int* __restrict__ dropped_idx,
                    const unsigned long long* __restrict__ assign_key,
                    float* __restrict__ score_accum, float* __restrict__ out_tok)
{
    const int g = blockIdx.x;                   // [0, B*M)
    const int b = g / M_, /*m,*/ koff = 0; (void)koff;
    const unsigned long long key = assign_key[g];
    const int k = (int)(0xFFFFFFFFu - (unsigned)(key & 0xFFFFFFFFull));
    const int dIdx = dropped_idx[g];
    const float s = fmaxf(scores[b * N_ + dIdx], 0.0f);
    if (threadIdx.x == 0) atomicAdd(&score_accum[b * K_ + k], s);
    const float* src = tokens + ((size_t)b * N_ + dIdx) * D_;
    float* dst = out_tok + ((size_t)b * K_ + k) * D_;
    const int o = threadIdx.x * 4;
    const float4 v = *(const float4*)(src + o);
    atomicAdd(dst + o + 0, s * v.x);
    atomicAdd(dst + o + 1, s * v.y);
    atomicAdd(dst + o + 2, s * v.z);
    atomicAdd(dst + o + 3, s * v.w);
}

// ---------------------------------------------------------------------------
// Kernel 5: divide each merged row by max(k_sc + sum(d_sc), EPS).
// ---------------------------------------------------------------------------
__global__ __launch_bounds__(256)
void finalize_kernel(const float* __restrict__ kept_sc,
                     const float* __restrict__ score_accum,
                     float* __restrict__ out_tok)
{
    const int r = blockIdx.x;                   // [0, B*K)
    const float denom = fmaxf(kept_sc[r] + score_accum[r], 1e-6f);
    const float inv = 1.0f / denom;
    float* p = out_tok + (size_t)r * D_;
    const int o = threadIdx.x * 4;
    float4 v = *(float4*)(p + o);
    v.x *= inv; v.y *= inv; v.z *= inv; v.w *= inv;
    *(float4*)(p + o) = v;
}

// ---------------------------------------------------------------------------
extern "C" void kernel_launch(void* const* d_in, const int* in_sizes, int n_in,
                              void* d_out, int out_size, void* d_ws, size_t ws_size,
                              hipStream_t stream)
{
    const float* tokens = (const float*)d_in[0];
    const float* scores = (const float*)d_in[1];

    float* out = (float*)d_out;
    float* out_tok = out;                              // [B,K,D] merged tokens
    float* out_idx = out + (size_t)B_ * K_ * D_;       // [B,K] indices (as float)
    float* out_sc  = out_idx + (size_t)B_ * K_;        // [B,K] kept scores

    char* ws = (char*)d_ws;
    int*   kept_idx    = (int*)(ws);                   //  64 KB
    int*   dropped_idx = (int*)(ws + 65536);           // 192 KB
    float* kept_sc     = (float*)(ws + 262144);        //  64 KB
    float* inv_knorm   = (float*)(ws + 327680);        //  64 KB
    float* score_accum = (float*)(ws + 393216);        //  64 KB
    unsigned long long* assign_key =
        (unsigned long long*)(ws + 458752);            // 384 KB

    topk_kernel<<<B_, 1024, 0, stream>>>(scores, out_idx, out_sc,
                                         kept_idx, dropped_idx, kept_sc, assign_key);

    prep_kernel<<<(B_ * K_) / 4, 256, 0, stream>>>(tokens, kept_idx, kept_sc,
                                                   inv_knorm, score_accum, out_tok);

    dim3 g3(K_ / TBK, M_ / TBM, B_);
    sim_argmax_kernel<<<g3, 256, 0, stream>>>(tokens, kept_idx, dropped_idx,
                                              inv_knorm, assign_key);

    scatter_kernel<<<B_ * M_, 256, 0, stream>>>(tokens, scores, dropped_idx,
                                                assign_key, score_accum, out_tok);

    finalize_kernel<<<B_ * K_, 256, 0, stream>>>(kept_sc, score_accum, out_tok);
}

// Round 2
// 1573.605 us; speedup vs baseline: 1.5013x; 1.5013x over previous
//
#include <hip/hip_runtime.h>
#include <hip/hip_bf16.h>

#define B_ 16
#define N_ 4096
#define D_ 1024
#define K_ 1024
#define M_ 3072

typedef unsigned short u16;
typedef __attribute__((ext_vector_type(8))) short bf16x8;
typedef __attribute__((ext_vector_type(4))) float f32x4;

// round-to-nearest-even fp32 -> bf16
__device__ inline u16 bf16_rn(float x) {
    unsigned u = __float_as_uint(x);
    u += 0x7fffu + ((u >> 16) & 1u);
    return (u16)(u >> 16);
}
__device__ inline void bf16_split(float x, u16& h, u16& l) {
    h = bf16_rn(x);
    const float hf = __uint_as_float(((unsigned)h) << 16);
    l = bf16_rn(x - hf);
}

// ---------------------------------------------------------------------------
// Kernel 1: per-batch top-K selection (JAX tie semantics), kept ascending,
// dropped ascending. One block per batch; bitonic sort of u64 keys in LDS.
// ---------------------------------------------------------------------------
__global__ __launch_bounds__(1024)
void topk_kernel(const float* __restrict__ scores,
                 float* __restrict__ out_idx_f, float* __restrict__ out_sc,
                 int* __restrict__ kept_idx, int* __restrict__ dropped_idx,
                 float* __restrict__ kept_sc,
                 unsigned long long* __restrict__ assign_key)
{
    const int b = blockIdx.x;
    const int tid = threadIdx.x;
    __shared__ unsigned long long keys[N_];
    __shared__ unsigned wsum[16];

    for (int m = tid; m < M_; m += 1024) assign_key[b * M_ + m] = 0ull;

    for (int i = tid; i < N_; i += 1024) {
        float s = scores[b * N_ + i];
        unsigned sb = __float_as_uint(s);
        sb = (sb & 0x80000000u) ? ~sb : (sb | 0x80000000u);
        keys[i] = ((unsigned long long)sb << 32) | (unsigned)(N_ - 1 - i);
    }
    __syncthreads();

    for (unsigned k = 2; k <= (unsigned)N_; k <<= 1) {
        for (unsigned j = k >> 1; j > 0; j >>= 1) {
            for (unsigned i = tid; i < (unsigned)N_; i += 1024) {
                unsigned ixj = i ^ j;
                if (ixj > i) {
                    unsigned long long a = keys[i], c = keys[ixj];
                    bool up = ((i & k) == 0);
                    if ((a > c) == up) { keys[i] = c; keys[ixj] = a; }
                }
            }
            __syncthreads();
        }
    }

    const unsigned long long thr = keys[N_ - K_];
    const int lane = tid & 63, w = tid >> 6;
    unsigned carry = 0;

    for (int r = 0; r < 4; ++r) {
        const int e = r * 1024 + tid;
        const float s = scores[b * N_ + e];
        unsigned sb = __float_as_uint(s);
        sb = (sb & 0x80000000u) ? ~sb : (sb | 0x80000000u);
        const unsigned long long key =
            ((unsigned long long)sb << 32) | (unsigned)(N_ - 1 - e);
        const bool kept = (key >= thr);

        const unsigned long long mb = __ballot(kept);
        const unsigned lanePre = (unsigned)__popcll(mb & ((1ull << lane) - 1ull));
        if (lane == 0) wsum[w] = (unsigned)__popcll(mb);
        __syncthreads();
        unsigned waveExcl = 0, roundTot = 0;
        for (int i = 0; i < 16; ++i) {
            unsigned v = wsum[i];
            if (i < w) waveExcl += v;
            roundTot += v;
        }
        const unsigned kpos = carry + waveExcl + lanePre;
        if (kept) {
            out_idx_f[b * K_ + kpos] = (float)e;
            out_sc  [b * K_ + kpos] = s;
            kept_idx[b * K_ + kpos] = e;
            kept_sc [b * K_ + kpos] = fmaxf(s, 0.0f);
        } else {
            const unsigned q = (unsigned)e - kpos;
            dropped_idx[b * M_ + q] = e;
        }
        carry += roundTot;
        __syncthreads();
    }
}

// ---------------------------------------------------------------------------
// Kernel 2: per kept token -- inv L2 norm, init out = kept * relu(score),
// zero score accumulator, and write normalized bf16 hi/lo split (for MFMA sim).
// One wave per kept token.
// ---------------------------------------------------------------------------
__global__ __launch_bounds__(256)
void prep_kernel(const float* __restrict__ tokens,
                 const int* __restrict__ kept_idx, const float* __restrict__ kept_sc,
                 float* __restrict__ inv_knorm, float* __restrict__ score_accum,
                 float* __restrict__ out_tok,
                 u16* __restrict__ khi, u16* __restrict__ klo, int do_split)
{
    const int w = threadIdx.x >> 6, lane = threadIdx.x & 63;
    const int g = blockIdx.x * 4 + w;          // [0, B*K)
    const int b = g >> 10;                     // K_ = 1024
    const int idx = kept_idx[g];
    const float* src = tokens + ((size_t)b * N_ + idx) * D_;

    float4 v[4];
    float ss = 0.0f;
#pragma unroll
    for (int j = 0; j < 4; ++j) {
        v[j] = *(const float4*)(src + (lane + j * 64) * 4);
        ss += v[j].x * v[j].x + v[j].y * v[j].y + v[j].z * v[j].z + v[j].w * v[j].w;
    }
#pragma unroll
    for (int sh = 1; sh < 64; sh <<= 1) ss += __shfl_xor(ss, sh, 64);

    const float inv = 1.0f / fmaxf(sqrtf(ss), 1e-12f);
    const float ksc = kept_sc[g];
    float* dst = out_tok + (size_t)g * D_;
#pragma unroll
    for (int j = 0; j < 4; ++j) {
        float4 o;
        o.x = v[j].x * ksc; o.y = v[j].y * ksc; o.z = v[j].z * ksc; o.w = v[j].w * ksc;
        *(float4*)(dst + (lane + j * 64) * 4) = o;
    }
    if (do_split) {
        u16* hp = khi + (size_t)g * D_;
        u16* lp = klo + (size_t)g * D_;
#pragma unroll
        for (int j = 0; j < 4; ++j) {
            ushort4 h, l;
            bf16_split(v[j].x * inv, h.x, l.x);
            bf16_split(v[j].y * inv, h.y, l.y);
            bf16_split(v[j].z * inv, h.z, l.z);
            bf16_split(v[j].w * inv, h.w, l.w);
            *(ushort4*)(hp + 4 * (lane + 64 * j)) = h;
            *(ushort4*)(lp + 4 * (lane + 64 * j)) = l;
        }
    }
    if (lane == 0) { inv_knorm[g] = inv; score_accum[g] = 0.0f; }
}

// ---------------------------------------------------------------------------
// Kernel 2b: gather dropped rows and write bf16 hi/lo split (unnormalized --
// per-row positive scale is argmax-invariant). One wave per dropped token.
// ---------------------------------------------------------------------------
__global__ __launch_bounds__(256)
void conv_dropped_kernel(const float* __restrict__ tokens,
                         const int* __restrict__ dropped_idx,
                         u16* __restrict__ dhi, u16* __restrict__ dlo)
{
    const int w = threadIdx.x >> 6, lane = threadIdx.x & 63;
    const int g = blockIdx.x * 4 + w;          // [0, B*M)
    const int b = g / M_;
    const int idx = dropped_idx[g];
    const float* src = tokens + ((size_t)b * N_ + idx) * D_;
    u16* hp = dhi + (size_t)g * D_;
    u16* lp = dlo + (size_t)g * D_;
#pragma unroll
    for (int j = 0; j < 4; ++j) {
        const float4 v = *(const float4*)(src + (lane + j * 64) * 4);
        ushort4 h, l;
        bf16_split(v.x, h.x, l.x);
        bf16_split(v.y, h.y, l.y);
        bf16_split(v.z, h.z, l.z);
        bf16_split(v.w, h.w, l.w);
        *(ushort4*)(hp + 4 * (lane + 64 * j)) = h;
        *(ushort4*)(lp + 4 * (lane + 64 * j)) = l;
    }
}

// ---------------------------------------------------------------------------
// Kernel 3 (MFMA): sim = dropped . kept_norm^T via 3-pass split-bf16
// (hh + hl + lh; lo*lo term ~2^-18 rel, below fp32 reorder noise).
// Tile 128(M) x 128(N), BK=32. LDS layout == MFMA fragment order:
// per 16x32 block, 1KB, lane l holds row (l&15), k = (l>>4)*8..+8 at l*16B.
// Staged with global_load_lds width=16 (LDS dst = uniform base + lane*16).
// Fused row-argmax via packed u64 atomicMax (max sim, tie -> min n).
// ---------------------------------------------------------------------------
__global__ __launch_bounds__(256)
void sim_mfma_kernel(const u16* __restrict__ dhi, const u16* __restrict__ dlo,
                     const u16* __restrict__ khi, const u16* __restrict__ klo,
                     unsigned long long* __restrict__ assign_key)
{
    const int b = blockIdx.z, mt = blockIdx.y, nt = blockIdx.x;
    const int tid = threadIdx.x, w = tid >> 6, lane = tid & 63;
    const int lrow = lane >> 4, lcol = lane & 15;
    __shared__ __align__(16) char smem[32768];   // Ah | Al | Bh | Bl (8KB each)

    const u16* mat;
    if      (w == 0) mat = dhi + ((size_t)b * M_ + mt * 128) * D_;
    else if (w == 1) mat = dlo + ((size_t)b * M_ + mt * 128) * D_;
    else if (w == 2) mat = khi + ((size_t)b * K_ + nt * 128) * D_;
    else             mat = klo + ((size_t)b * K_ + nt * 128) * D_;
    char* ldsbase = smem + w * 8192;

    const int wm = (w & 1) * 64, wn = (w >> 1) * 64;

    f32x4 acc[4][4];
#pragma unroll
    for (int i = 0; i < 4; ++i)
#pragma unroll
        for (int j = 0; j < 4; ++j)
            acc[i][j] = (f32x4){0.f, 0.f, 0.f, 0.f};

    for (int k0 = 0; k0 < D_; k0 += 32) {
        __syncthreads();   // LDS free from previous chunk's reads
#pragma unroll
        for (int s = 0; s < 8; ++s) {
            const u16* gp = mat + (size_t)(s * 16 + lcol) * D_ + k0 + lrow * 8;
            __builtin_amdgcn_global_load_lds(
                (const __attribute__((address_space(1))) void*)gp,
                (__attribute__((address_space(3))) void*)(ldsbase + s * 1024),
                16, 0, 0);
        }
        __syncthreads();   // drains vmcnt before barrier

        bf16x8 ah[4], al[4], bh[4], bl[4];
#pragma unroll
        for (int i = 0; i < 4; ++i) {
            ah[i] = *(const bf16x8*)(smem +     0 + (wm / 16 + i) * 1024 + lane * 16);
            al[i] = *(const bf16x8*)(smem +  8192 + (wm / 16 + i) * 1024 + lane * 16);
            bh[i] = *(const bf16x8*)(smem + 16384 + (wn / 16 + i) * 1024 + lane * 16);
            bl[i] = *(const bf16x8*)(smem + 24576 + (wn / 16 + i) * 1024 + lane * 16);
        }
#pragma unroll
        for (int i = 0; i < 4; ++i)
#pragma unroll
            for (int j = 0; j < 4; ++j) {
                acc[i][j] = __builtin_amdgcn_mfma_f32_16x16x32_bf16(al[i], bh[j], acc[i][j], 0, 0, 0);
                acc[i][j] = __builtin_amdgcn_mfma_f32_16x16x32_bf16(ah[i], bl[j], acc[i][j], 0, 0, 0);
                acc[i][j] = __builtin_amdgcn_mfma_f32_16x16x32_bf16(ah[i], bh[j], acc[i][j], 0, 0, 0);
            }
    }

    // epilogue: per-row argmax.  C layout: col = lane&15, row = (lane>>4)*4+reg.
#pragma unroll
    for (int i = 0; i < 4; ++i) {
#pragma unroll
        for (int r = 0; r < 4; ++r) {
            float bv = acc[i][0][r];
            int   bn = wn + lcol;
#pragma unroll
            for (int j = 1; j < 4; ++j) {
                const float v = acc[i][j][r];
                if (v > bv) { bv = v; bn = wn + j * 16 + lcol; }
            }
            unsigned u = __float_as_uint(bv);
            u = (u & 0x80000000u) ? ~u : (u | 0x80000000u);
            unsigned long long key = ((unsigned long long)u << 32)
                                   | (unsigned long long)(0xFFFFFFFFu - (unsigned)(nt * 128 + bn));
#pragma unroll
            for (int sh = 1; sh < 16; sh <<= 1) {
                const unsigned long long o = __shfl_xor(key, sh, 64);
                if (o > key) key = o;
            }
            if (lcol == 0) {
                const int m = mt * 128 + wm + i * 16 + lrow * 4 + r;
                atomicMax(&assign_key[b * M_ + m], key);
            }
        }
    }
}

// ---------------------------------------------------------------------------
// Kernel 3 (fallback, fp32 VALU): used only if ws_size is too small.
// ---------------------------------------------------------------------------
#define TBM 64
#define TBK 64
#define TBD 16
#define LDA 68

__global__ __launch_bounds__(256)
void sim_argmax_kernel(const float* __restrict__ tokens,
                       const int* __restrict__ kept_idx,
                       const int* __restrict__ dropped_idx,
                       const float* __restrict__ inv_knorm,
                       unsigned long long* __restrict__ assign_key)
{
    const int b = blockIdx.z, mt = blockIdx.y, kt = blockIdx.x;
    const int tid = threadIdx.x;
    __shared__ float As[TBD * LDA], Bs[TBD * LDA];

    const int srow = tid >> 2, sc4 = tid & 3;
    const int aTok = dropped_idx[b * M_ + mt * TBM + srow];
    const int bTok = kept_idx  [b * K_ + kt * TBK + srow];
    const float* aSrc = tokens + ((size_t)b * N_ + aTok) * D_ + sc4 * 4;
    const float* bSrc = tokens + ((size_t)b * N_ + bTok) * D_ + sc4 * 4;

    const int tx = tid & 15, ty = tid >> 4;
    float acc[4][4] = {{0.f}};

    for (int d0 = 0; d0 < D_; d0 += TBD) {
        const float4 av = *(const float4*)(aSrc + d0);
        const float4 bv = *(const float4*)(bSrc + d0);
        __syncthreads();
        As[(sc4 * 4 + 0) * LDA + srow] = av.x;
        As[(sc4 * 4 + 1) * LDA + srow] = av.y;
        As[(sc4 * 4 + 2) * LDA + srow] = av.z;
        As[(sc4 * 4 + 3) * LDA + srow] = av.w;
        Bs[(sc4 * 4 + 0) * LDA + srow] = bv.x;
        Bs[(sc4 * 4 + 1) * LDA + srow] = bv.y;
        Bs[(sc4 * 4 + 2) * LDA + srow] = bv.z;
        Bs[(sc4 * 4 + 3) * LDA + srow] = bv.w;
        __syncthreads();
#pragma unroll
        for (int d = 0; d < TBD; ++d) {
            const float4 a4 = *(const float4*)&As[d * LDA + ty * 4];
            const float4 b4 = *(const float4*)&Bs[d * LDA + tx * 4];
            acc[0][0] += a4.x * b4.x; acc[0][1] += a4.x * b4.y;
            acc[0][2] += a4.x * b4.z; acc[0][3] += a4.x * b4.w;
            acc[1][0] += a4.y * b4.x; acc[1][1] += a4.y * b4.y;
            acc[1][2] += a4.y * b4.z; acc[1][3] += a4.y * b4.w;
            acc[2][0] += a4.z * b4.x; acc[2][1] += a4.z * b4.y;
            acc[2][2] += a4.z * b4.z; acc[2][3] += a4.z * b4.w;
            acc[3][0] += a4.w * b4.x; acc[3][1] += a4.w * b4.y;
            acc[3][2] += a4.w * b4.z; acc[3][3] += a4.w * b4.w;
        }
    }

    float invk[4];
#pragma unroll
    for (int j = 0; j < 4; ++j) invk[j] = inv_knorm[b * K_ + kt * TBK + tx * 4 + j];

#pragma unroll
    for (int i = 0; i < 4; ++i) {
        float bestv = acc[i][0] * invk[0];
        int bestk = kt * TBK + tx * 4;
#pragma unroll
        for (int j = 1; j < 4; ++j) {
            const float v = acc[i][j] * invk[j];
            if (v > bestv) { bestv = v; bestk = kt * TBK + tx * 4 + j; }
        }
        unsigned u = __float_as_uint(bestv);
        u = (u & 0x80000000u) ? ~u : (u | 0x80000000u);
        unsigned long long key = ((unsigned long long)u << 32)
                               | (unsigned long long)(0xFFFFFFFFu - (unsigned)bestk);
#pragma unroll
        for (int sh = 1; sh < 16; sh <<= 1) {
            unsigned lo = (unsigned)key, hi = (unsigned)(key >> 32);
            lo = __shfl_xor(lo, sh, 64);
            hi = __shfl_xor(hi, sh, 64);
            const unsigned long long o = ((unsigned long long)hi << 32) | lo;
            if (o > key) key = o;
        }
        if (tx == 0) {
            const int mg = mt * TBM + ty * 4 + i;
            atomicMax(&assign_key[b * M_ + mg], key);
        }
    }
}

// ---------------------------------------------------------------------------
// Kernel 4: scatter weighted dropped tokens into assigned kept rows.
// ---------------------------------------------------------------------------
__global__ __launch_bounds__(256)
void scatter_kernel(const float* __restrict__ tokens, const float* __restrict__ scores,
                    const int* __restrict__ dropped_idx,
                    const unsigned long long* __restrict__ assign_key,
                    float* __restrict__ score_accum, float* __restrict__ out_tok)
{
    const int g = blockIdx.x;                   // [0, B*M)
    const int b = g / M_;
    const unsigned long long key = assign_key[g];
    const int k = (int)(0xFFFFFFFFu - (unsigned)(key & 0xFFFFFFFFull));
    const int dIdx = dropped_idx[g];
    const float s = fmaxf(scores[b * N_ + dIdx], 0.0f);
    if (threadIdx.x == 0) atomicAdd(&score_accum[b * K_ + k], s);
    const float* src = tokens + ((size_t)b * N_ + dIdx) * D_;
    float* dst = out_tok + ((size_t)b * K_ + k) * D_;
    const int o = threadIdx.x * 4;
    const float4 v = *(const float4*)(src + o);
    atomicAdd(dst + o + 0, s * v.x);
    atomicAdd(dst + o + 1, s * v.y);
    atomicAdd(dst + o + 2, s * v.z);
    atomicAdd(dst + o + 3, s * v.w);
}

// ---------------------------------------------------------------------------
// Kernel 5: divide each merged row by max(k_sc + sum(d_sc), EPS).
// ---------------------------------------------------------------------------
__global__ __launch_bounds__(256)
void finalize_kernel(const float* __restrict__ kept_sc,
                     const float* __restrict__ score_accum,
                     float* __restrict__ out_tok)
{
    const int r = blockIdx.x;                   // [0, B*K)
    const float denom = fmaxf(kept_sc[r] + score_accum[r], 1e-6f);
    const float inv = 1.0f / denom;
    float* p = out_tok + (size_t)r * D_;
    const int o = threadIdx.x * 4;
    float4 v = *(float4*)(p + o);
    v.x *= inv; v.y *= inv; v.z *= inv; v.w *= inv;
    *(float4*)(p + o) = v;
}

// ---------------------------------------------------------------------------
extern "C" void kernel_launch(void* const* d_in, const int* in_sizes, int n_in,
                              void* d_out, int out_size, void* d_ws, size_t ws_size,
                              hipStream_t stream)
{
    const float* tokens = (const float*)d_in[0];
    const float* scores = (const float*)d_in[1];

    float* out = (float*)d_out;
    float* out_tok = out;                              // [B,K,D]
    float* out_idx = out + (size_t)B_ * K_ * D_;       // [B,K]
    float* out_sc  = out_idx + (size_t)B_ * K_;        // [B,K]

    char* ws = (char*)d_ws;
    int*   kept_idx    = (int*)(ws);                   //  64 KB
    int*   dropped_idx = (int*)(ws + 65536);           // 192 KB
    float* kept_sc     = (float*)(ws + 262144);        //  64 KB
    float* inv_knorm   = (float*)(ws + 327680);        //  64 KB
    float* score_accum = (float*)(ws + 393216);        //  64 KB
    unsigned long long* assign_key =
        (unsigned long long*)(ws + 458752);            // 384 KB

    const size_t kSplit = (size_t)B_ * K_ * D_ * 2;    // 32 MB each
    const size_t dSplit = (size_t)B_ * M_ * D_ * 2;    // 96 MB each
    u16* khi = (u16*)(ws + (1u << 20));
    u16* klo = (u16*)((char*)khi + kSplit);
    u16* dhi = (u16*)((char*)klo + kSplit);
    u16* dlo = (u16*)((char*)dhi + dSplit);
    const size_t need = (1u << 20) + 2 * kSplit + 2 * dSplit;
    const int use_mfma = (ws_size >= need) ? 1 : 0;

    topk_kernel<<<B_, 1024, 0, stream>>>(scores, out_idx, out_sc,
                                         kept_idx, dropped_idx, kept_sc, assign_key);

    prep_kernel<<<(B_ * K_) / 4, 256, 0, stream>>>(tokens, kept_idx, kept_sc,
                                                   inv_knorm, score_accum, out_tok,
                                                   khi, klo, use_mfma);

    if (use_mfma) {
        conv_dropped_kernel<<<(B_ * M_) / 4, 256, 0, stream>>>(tokens, dropped_idx,
                                                               dhi, dlo);
        dim3 g3(K_ / 128, M_ / 128, B_);
        sim_mfma_kernel<<<g3, 256, 0, stream>>>(dhi, dlo, khi, klo, assign_key);
    } else {
        dim3 g3(K_ / TBK, M_ / TBM, B_);
        sim_argmax_kernel<<<g3, 256, 0, stream>>>(tokens, kept_idx, dropped_idx,
                                                  inv_knorm, assign_key);
    }

    scatter_kernel<<<B_ * M_, 256, 0, stream>>>(tokens, scores, dropped_idx,
                                                assign_key, score_accum, out_tok);

    finalize_kernel<<<B_ * K_, 256, 0, stream>>>(kept_sc, score_accum, out_tok);
}

// Round 3
// 949.163 us; speedup vs baseline: 2.4890x; 1.6579x over previous
//
#include <hip/hip_runtime.h>
#include <hip/hip_bf16.h>

#define B_ 16
#define N_ 4096
#define D_ 1024
#define K_ 1024
#define M_ 3072

typedef unsigned short u16;
typedef unsigned int u32;
typedef __attribute__((ext_vector_type(8))) short bf16x8;
typedef __attribute__((ext_vector_type(4))) float f32x4;

// round-to-nearest-even fp32 -> bf16
__device__ inline u16 bf16_rn(float x) {
    unsigned u = __float_as_uint(x);
    u += 0x7fffu + ((u >> 16) & 1u);
    return (u16)(u >> 16);
}
__device__ inline void bf16_split(float x, u16& h, u16& l) {
    h = bf16_rn(x);
    const float hf = __uint_as_float(((unsigned)h) << 16);
    l = bf16_rn(x - hf);
}

// ---------------------------------------------------------------------------
// Kernel 1: per-batch top-K selection (JAX tie semantics), kept ascending,
// dropped ascending. One block per batch; bitonic sort of u64 keys in LDS.
// ---------------------------------------------------------------------------
__global__ __launch_bounds__(1024)
void topk_kernel(const float* __restrict__ scores,
                 float* __restrict__ out_idx_f, float* __restrict__ out_sc,
                 int* __restrict__ kept_idx, int* __restrict__ dropped_idx,
                 float* __restrict__ kept_sc,
                 unsigned long long* __restrict__ assign_key)
{
    const int b = blockIdx.x;
    const int tid = threadIdx.x;
    __shared__ unsigned long long keys[N_];
    __shared__ unsigned wsum[16];

    for (int m = tid; m < M_; m += 1024) assign_key[b * M_ + m] = 0ull;

    for (int i = tid; i < N_; i += 1024) {
        float s = scores[b * N_ + i];
        unsigned sb = __float_as_uint(s);
        sb = (sb & 0x80000000u) ? ~sb : (sb | 0x80000000u);
        keys[i] = ((unsigned long long)sb << 32) | (unsigned)(N_ - 1 - i);
    }
    __syncthreads();

    for (unsigned k = 2; k <= (unsigned)N_; k <<= 1) {
        for (unsigned j = k >> 1; j > 0; j >>= 1) {
            for (unsigned i = tid; i < (unsigned)N_; i += 1024) {
                unsigned ixj = i ^ j;
                if (ixj > i) {
                    unsigned long long a = keys[i], c = keys[ixj];
                    bool up = ((i & k) == 0);
                    if ((a > c) == up) { keys[i] = c; keys[ixj] = a; }
                }
            }
            __syncthreads();
        }
    }

    const unsigned long long thr = keys[N_ - K_];
    const int lane = tid & 63, w = tid >> 6;
    unsigned carry = 0;

    for (int r = 0; r < 4; ++r) {
        const int e = r * 1024 + tid;
        const float s = scores[b * N_ + e];
        unsigned sb = __float_as_uint(s);
        sb = (sb & 0x80000000u) ? ~sb : (sb | 0x80000000u);
        const unsigned long long key =
            ((unsigned long long)sb << 32) | (unsigned)(N_ - 1 - e);
        const bool kept = (key >= thr);

        const unsigned long long mb = __ballot(kept);
        const unsigned lanePre = (unsigned)__popcll(mb & ((1ull << lane) - 1ull));
        if (lane == 0) wsum[w] = (unsigned)__popcll(mb);
        __syncthreads();
        unsigned waveExcl = 0, roundTot = 0;
        for (int i = 0; i < 16; ++i) {
            unsigned v = wsum[i];
            if (i < w) waveExcl += v;
            roundTot += v;
        }
        const unsigned kpos = carry + waveExcl + lanePre;
        if (kept) {
            out_idx_f[b * K_ + kpos] = (float)e;
            out_sc  [b * K_ + kpos] = s;
            kept_idx[b * K_ + kpos] = e;
            kept_sc [b * K_ + kpos] = fmaxf(s, 0.0f);
        } else {
            const unsigned q = (unsigned)e - kpos;
            dropped_idx[b * M_ + q] = e;
        }
        carry += roundTot;
        __syncthreads();
    }
}

// ---------------------------------------------------------------------------
// Kernel 2: per kept token -- inv L2 norm, normalized bf16 hi/lo split,
// zero the per-slot counters. One wave per kept token.
// ---------------------------------------------------------------------------
__global__ __launch_bounds__(256)
void prep_kernel(const float* __restrict__ tokens,
                 const int* __restrict__ kept_idx,
                 float* __restrict__ inv_knorm, u32* __restrict__ count,
                 u16* __restrict__ khi, u16* __restrict__ klo, int do_split)
{
    const int w = threadIdx.x >> 6, lane = threadIdx.x & 63;
    const int g = blockIdx.x * 4 + w;          // [0, B*K)
    const int b = g >> 10;                     // K_ = 1024
    const int idx = kept_idx[g];
    const float* src = tokens + ((size_t)b * N_ + idx) * D_;

    float4 v[4];
    float ss = 0.0f;
#pragma unroll
    for (int j = 0; j < 4; ++j) {
        v[j] = *(const float4*)(src + (lane + j * 64) * 4);
        ss += v[j].x * v[j].x + v[j].y * v[j].y + v[j].z * v[j].z + v[j].w * v[j].w;
    }
#pragma unroll
    for (int sh = 1; sh < 64; sh <<= 1) ss += __shfl_xor(ss, sh, 64);

    const float inv = 1.0f / fmaxf(sqrtf(ss), 1e-12f);
    if (do_split) {
        u16* hp = khi + (size_t)g * D_;
        u16* lp = klo + (size_t)g * D_;
#pragma unroll
        for (int j = 0; j < 4; ++j) {
            ushort4 h, l;
            bf16_split(v[j].x * inv, h.x, l.x);
            bf16_split(v[j].y * inv, h.y, l.y);
            bf16_split(v[j].z * inv, h.z, l.z);
            bf16_split(v[j].w * inv, h.w, l.w);
            *(ushort4*)(hp + 4 * (lane + 64 * j)) = h;
            *(ushort4*)(lp + 4 * (lane + 64 * j)) = l;
        }
    }
    if (lane == 0) { inv_knorm[g] = inv; count[g] = 0u; }
}

// ---------------------------------------------------------------------------
// Kernel 2b: gather dropped rows, write bf16 hi/lo split (unnormalized --
// per-row positive scale is argmax-invariant). One wave per dropped token.
// ---------------------------------------------------------------------------
__global__ __launch_bounds__(256)
void conv_dropped_kernel(const float* __restrict__ tokens,
                         const int* __restrict__ dropped_idx,
                         u16* __restrict__ dhi, u16* __restrict__ dlo)
{
    const int w = threadIdx.x >> 6, lane = threadIdx.x & 63;
    const int g = blockIdx.x * 4 + w;          // [0, B*M)
    const int b = g / M_;
    const int idx = dropped_idx[g];
    const float* src = tokens + ((size_t)b * N_ + idx) * D_;
    u16* hp = dhi + (size_t)g * D_;
    u16* lp = dlo + (size_t)g * D_;
#pragma unroll
    for (int j = 0; j < 4; ++j) {
        const float4 v = *(const float4*)(src + (lane + j * 64) * 4);
        ushort4 h, l;
        bf16_split(v.x, h.x, l.x);
        bf16_split(v.y, h.y, l.y);
        bf16_split(v.z, h.z, l.z);
        bf16_split(v.w, h.w, l.w);
        *(ushort4*)(hp + 4 * (lane + 64 * j)) = h;
        *(ushort4*)(lp + 4 * (lane + 64 * j)) = l;
    }
}

// ---------------------------------------------------------------------------
// Kernel 3 (MFMA): sim = dropped . kept_norm^T via 3-pass split-bf16.
// Tile 128x128, BK=32. LDS layout == MFMA fragment order; staged with
// global_load_lds width=16. Fused row-argmax via packed u64 atomicMax.
// ---------------------------------------------------------------------------
__global__ __launch_bounds__(256)
void sim_mfma_kernel(const u16* __restrict__ dhi, const u16* __restrict__ dlo,
                     const u16* __restrict__ khi, const u16* __restrict__ klo,
                     unsigned long long* __restrict__ assign_key)
{
    const int b = blockIdx.z, mt = blockIdx.y, nt = blockIdx.x;
    const int tid = threadIdx.x, w = tid >> 6, lane = tid & 63;
    const int lrow = lane >> 4, lcol = lane & 15;
    __shared__ __align__(16) char smem[32768];   // Ah | Al | Bh | Bl (8KB each)

    const u16* mat;
    if      (w == 0) mat = dhi + ((size_t)b * M_ + mt * 128) * D_;
    else if (w == 1) mat = dlo + ((size_t)b * M_ + mt * 128) * D_;
    else if (w == 2) mat = khi + ((size_t)b * K_ + nt * 128) * D_;
    else             mat = klo + ((size_t)b * K_ + nt * 128) * D_;
    char* ldsbase = smem + w * 8192;

    const int wm = (w & 1) * 64, wn = (w >> 1) * 64;

    f32x4 acc[4][4];
#pragma unroll
    for (int i = 0; i < 4; ++i)
#pragma unroll
        for (int j = 0; j < 4; ++j)
            acc[i][j] = (f32x4){0.f, 0.f, 0.f, 0.f};

    for (int k0 = 0; k0 < D_; k0 += 32) {
        __syncthreads();
#pragma unroll
        for (int s = 0; s < 8; ++s) {
            const u16* gp = mat + (size_t)(s * 16 + lcol) * D_ + k0 + lrow * 8;
            __builtin_amdgcn_global_load_lds(
                (const __attribute__((address_space(1))) void*)gp,
                (__attribute__((address_space(3))) void*)(ldsbase + s * 1024),
                16, 0, 0);
        }
        __syncthreads();

        bf16x8 ah[4], al[4], bh[4], bl[4];
#pragma unroll
        for (int i = 0; i < 4; ++i) {
            ah[i] = *(const bf16x8*)(smem +     0 + (wm / 16 + i) * 1024 + lane * 16);
            al[i] = *(const bf16x8*)(smem +  8192 + (wm / 16 + i) * 1024 + lane * 16);
            bh[i] = *(const bf16x8*)(smem + 16384 + (wn / 16 + i) * 1024 + lane * 16);
            bl[i] = *(const bf16x8*)(smem + 24576 + (wn / 16 + i) * 1024 + lane * 16);
        }
#pragma unroll
        for (int i = 0; i < 4; ++i)
#pragma unroll
            for (int j = 0; j < 4; ++j) {
                acc[i][j] = __builtin_amdgcn_mfma_f32_16x16x32_bf16(al[i], bh[j], acc[i][j], 0, 0, 0);
                acc[i][j] = __builtin_amdgcn_mfma_f32_16x16x32_bf16(ah[i], bl[j], acc[i][j], 0, 0, 0);
                acc[i][j] = __builtin_amdgcn_mfma_f32_16x16x32_bf16(ah[i], bh[j], acc[i][j], 0, 0, 0);
            }
    }

    // epilogue: per-row argmax.  C layout: col = lane&15, row = (lane>>4)*4+reg.
#pragma unroll
    for (int i = 0; i < 4; ++i) {
#pragma unroll
        for (int r = 0; r < 4; ++r) {
            float bv = acc[i][0][r];
            int   bn = wn + lcol;
#pragma unroll
            for (int j = 1; j < 4; ++j) {
                const float v = acc[i][j][r];
                if (v > bv) { bv = v; bn = wn + j * 16 + lcol; }
            }
            unsigned u = __float_as_uint(bv);
            u = (u & 0x80000000u) ? ~u : (u | 0x80000000u);
            unsigned long long key = ((unsigned long long)u << 32)
                                   | (unsigned long long)(0xFFFFFFFFu - (unsigned)(nt * 128 + bn));
#pragma unroll
            for (int sh = 1; sh < 16; sh <<= 1) {
                const unsigned long long o = __shfl_xor(key, sh, 64);
                if (o > key) key = o;
            }
            if (lcol == 0) {
                const int m = mt * 128 + wm + i * 16 + lrow * 4 + r;
                atomicMax(&assign_key[b * M_ + m], key);
            }
        }
    }
}

// ---------------------------------------------------------------------------
// Kernel 3 (fallback, fp32 VALU): used only if ws_size is too small.
// ---------------------------------------------------------------------------
#define TBM 64
#define TBK 64
#define TBD 16
#define LDA 68

__global__ __launch_bounds__(256)
void sim_argmax_kernel(const float* __restrict__ tokens,
                       const int* __restrict__ kept_idx,
                       const int* __restrict__ dropped_idx,
                       const float* __restrict__ inv_knorm,
                       unsigned long long* __restrict__ assign_key)
{
    const int b = blockIdx.z, mt = blockIdx.y, kt = blockIdx.x;
    const int tid = threadIdx.x;
    __shared__ float As[TBD * LDA], Bs[TBD * LDA];

    const int srow = tid >> 2, sc4 = tid & 3;
    const int aTok = dropped_idx[b * M_ + mt * TBM + srow];
    const int bTok = kept_idx  [b * K_ + kt * TBK + srow];
    const float* aSrc = tokens + ((size_t)b * N_ + aTok) * D_ + sc4 * 4;
    const float* bSrc = tokens + ((size_t)b * N_ + bTok) * D_ + sc4 * 4;

    const int tx = tid & 15, ty = tid >> 4;
    float acc[4][4] = {{0.f}};

    for (int d0 = 0; d0 < D_; d0 += TBD) {
        const float4 av = *(const float4*)(aSrc + d0);
        const float4 bv = *(const float4*)(bSrc + d0);
        __syncthreads();
        As[(sc4 * 4 + 0) * LDA + srow] = av.x;
        As[(sc4 * 4 + 1) * LDA + srow] = av.y;
        As[(sc4 * 4 + 2) * LDA + srow] = av.z;
        As[(sc4 * 4 + 3) * LDA + srow] = av.w;
        Bs[(sc4 * 4 + 0) * LDA + srow] = bv.x;
        Bs[(sc4 * 4 + 1) * LDA + srow] = bv.y;
        Bs[(sc4 * 4 + 2) * LDA + srow] = bv.z;
        Bs[(sc4 * 4 + 3) * LDA + srow] = bv.w;
        __syncthreads();
#pragma unroll
        for (int d = 0; d < TBD; ++d) {
            const float4 a4 = *(const float4*)&As[d * LDA + ty * 4];
            const float4 b4 = *(const float4*)&Bs[d * LDA + tx * 4];
            acc[0][0] += a4.x * b4.x; acc[0][1] += a4.x * b4.y;
            acc[0][2] += a4.x * b4.z; acc[0][3] += a4.x * b4.w;
            acc[1][0] += a4.y * b4.x; acc[1][1] += a4.y * b4.y;
            acc[1][2] += a4.y * b4.z; acc[1][3] += a4.y * b4.w;
            acc[2][0] += a4.z * b4.x; acc[2][1] += a4.z * b4.y;
            acc[2][2] += a4.z * b4.z; acc[2][3] += a4.z * b4.w;
            acc[3][0] += a4.w * b4.x; acc[3][1] += a4.w * b4.y;
            acc[3][2] += a4.w * b4.z; acc[3][3] += a4.w * b4.w;
        }
    }

    float invk[4];
#pragma unroll
    for (int j = 0; j < 4; ++j) invk[j] = inv_knorm[b * K_ + kt * TBK + tx * 4 + j];

#pragma unroll
    for (int i = 0; i < 4; ++i) {
        float bestv = acc[i][0] * invk[0];
        int bestk = kt * TBK + tx * 4;
#pragma unroll
        for (int j = 1; j < 4; ++j) {
            const float v = acc[i][j] * invk[j];
            if (v > bestv) { bestv = v; bestk = kt * TBK + tx * 4 + j; }
        }
        unsigned u = __float_as_uint(bestv);
        u = (u & 0x80000000u) ? ~u : (u | 0x80000000u);
        unsigned long long key = ((unsigned long long)u << 32)
                               | (unsigned long long)(0xFFFFFFFFu - (unsigned)bestk);
#pragma unroll
        for (int sh = 1; sh < 16; sh <<= 1) {
            unsigned lo = (unsigned)key, hi = (unsigned)(key >> 32);
            lo = __shfl_xor(lo, sh, 64);
            hi = __shfl_xor(hi, sh, 64);
            const unsigned long long o = ((unsigned long long)hi << 32) | lo;
            if (o > key) key = o;
        }
        if (tx == 0) {
            const int mg = mt * TBM + ty * 4 + i;
            atomicMax(&assign_key[b * M_ + mg], key);
        }
    }
}

// ---------------------------------------------------------------------------
// Kernel 4a: count dropped tokens per kept slot.
// ---------------------------------------------------------------------------
__global__ __launch_bounds__(256)
void count_kernel(const unsigned long long* __restrict__ assign_key,
                  u32* __restrict__ count)
{
    const int g = blockIdx.x * 256 + threadIdx.x;   // [0, B*M)
    const int b = g / M_;
    const int k = (int)(0xFFFFFFFFu - (unsigned)(assign_key[g] & 0xFFFFFFFFull));
    atomicAdd(&count[b * K_ + k], 1u);
}

// ---------------------------------------------------------------------------
// Kernel 4b: per-batch exclusive scan of counts (K=1024); zero count for reuse
// as the fill cursor.
// ---------------------------------------------------------------------------
__global__ __launch_bounds__(1024)
void scan_kernel(u32* __restrict__ count, u32* __restrict__ offset)
{
    const int base = blockIdx.x * K_;
    const int t = threadIdx.x;
    __shared__ u32 sb[1024];
    const u32 c = count[base + t];
    sb[t] = c;
    __syncthreads();
    for (int d = 1; d < 1024; d <<= 1) {
        const u32 v = (t >= d) ? sb[t - d] : 0u;
        __syncthreads();
        sb[t] += v;
        __syncthreads();
    }
    offset[base + t] = sb[t] - c;
    count[base + t] = 0u;
}

// ---------------------------------------------------------------------------
// Kernel 4c: bucket-fill the per-slot dropped lists (count reused as cursor).
// ---------------------------------------------------------------------------
__global__ __launch_bounds__(256)
void fill_kernel(const unsigned long long* __restrict__ assign_key,
                 const u32* __restrict__ offset,
                 u32* __restrict__ count, u32* __restrict__ list)
{
    const int g = blockIdx.x * 256 + threadIdx.x;   // [0, B*M)
    const int b = g / M_;
    const int k = (int)(0xFFFFFFFFu - (unsigned)(assign_key[g] & 0xFFFFFFFFull));
    const u32 pos = atomicAdd(&count[b * K_ + k], 1u);
    list[b * M_ + offset[b * K_ + k] + pos] = (u32)g;
}

// ---------------------------------------------------------------------------
// Kernel 5: gather-merge. One block per kept slot: out =
// (kept*ksc + sum s*dropped) / max(ksc + sum s, EPS). No atomics.
// ---------------------------------------------------------------------------
__global__ __launch_bounds__(256)
void merge_kernel(const float* __restrict__ tokens, const float* __restrict__ scores,
                  const int* __restrict__ kept_idx, const float* __restrict__ kept_sc,
                  const int* __restrict__ dropped_idx,
                  const u32* __restrict__ offset, const u32* __restrict__ list,
                  float* __restrict__ out_tok)
{
    const int r = blockIdx.x;                   // [0, B*K)
    const int b = r >> 10;
    const int t = threadIdx.x;
    const u32 o = offset[r];
    const u32 e = ((r & (K_ - 1)) == K_ - 1) ? (u32)M_ : offset[r + 1];
    const float ksc = kept_sc[r];
    const int kIdx = kept_idx[r];

    float4 acc = *(const float4*)(tokens + ((size_t)b * N_ + kIdx) * D_ + t * 4);
    acc.x *= ksc; acc.y *= ksc; acc.z *= ksc; acc.w *= ksc;
    float ssum = 0.0f;

    for (u32 i = o; i < e; ++i) {
        const int g = (int)list[b * M_ + i];
        const int dIdx = dropped_idx[g];
        const float s = fmaxf(scores[b * N_ + dIdx], 0.0f);
        const float4 v = *(const float4*)(tokens + ((size_t)b * N_ + dIdx) * D_ + t * 4);
        acc.x += s * v.x; acc.y += s * v.y; acc.z += s * v.z; acc.w += s * v.w;
        ssum += s;
    }

    const float inv = 1.0f / fmaxf(ksc + ssum, 1e-6f);
    acc.x *= inv; acc.y *= inv; acc.z *= inv; acc.w *= inv;
    *(float4*)(out_tok + (size_t)r * D_ + t * 4) = acc;
}

// ---------------------------------------------------------------------------
extern "C" void kernel_launch(void* const* d_in, const int* in_sizes, int n_in,
                              void* d_out, int out_size, void* d_ws, size_t ws_size,
                              hipStream_t stream)
{
    const float* tokens = (const float*)d_in[0];
    const float* scores = (const float*)d_in[1];

    float* out = (float*)d_out;
    float* out_tok = out;                              // [B,K,D]
    float* out_idx = out + (size_t)B_ * K_ * D_;       // [B,K]
    float* out_sc  = out_idx + (size_t)B_ * K_;        // [B,K]

    char* ws = (char*)d_ws;
    int*   kept_idx    = (int*)(ws);                   //      0, 64 KB
    int*   dropped_idx = (int*)(ws + 65536);           //  64 KB, 192 KB
    float* kept_sc     = (float*)(ws + 262144);        // 256 KB, 64 KB
    float* inv_knorm   = (float*)(ws + 327680);        // 320 KB, 64 KB
    unsigned long long* assign_key =
        (unsigned long long*)(ws + 393216);            // 384 KB, 384 KB
    u32*   count       = (u32*)(ws + 786432);          // 768 KB, 64 KB
    u32*   offset      = (u32*)(ws + 851968);          // 832 KB, 64 KB
    u32*   list        = (u32*)(ws + 917504);          // 896 KB, 192 KB

    const size_t splitBase = 1179648;                  // 1.125 MB
    const size_t kSplit = (size_t)B_ * K_ * D_ * 2;    // 32 MB each
    const size_t dSplit = (size_t)B_ * M_ * D_ * 2;    // 96 MB each
    u16* khi = (u16*)(ws + splitBase);
    u16* klo = (u16*)((char*)khi + kSplit);
    u16* dhi = (u16*)((char*)klo + kSplit);
    u16* dlo = (u16*)((char*)dhi + dSplit);
    const size_t need = splitBase + 2 * kSplit + 2 * dSplit;
    const int use_mfma = (ws_size >= need) ? 1 : 0;

    topk_kernel<<<B_, 1024, 0, stream>>>(scores, out_idx, out_sc,
                                         kept_idx, dropped_idx, kept_sc, assign_key);

    prep_kernel<<<(B_ * K_) / 4, 256, 0, stream>>>(tokens, kept_idx,
                                                   inv_knorm, count,
                                                   khi, klo, use_mfma);

    if (use_mfma) {
        conv_dropped_kernel<<<(B_ * M_) / 4, 256, 0, stream>>>(tokens, dropped_idx,
                                                               dhi, dlo);
        dim3 g3(K_ / 128, M_ / 128, B_);
        sim_mfma_kernel<<<g3, 256, 0, stream>>>(dhi, dlo, khi, klo, assign_key);
    } else {
        dim3 g3(K_ / TBK, M_ / TBM, B_);
        sim_argmax_kernel<<<g3, 256, 0, stream>>>(tokens, kept_idx, dropped_idx,
                                                  inv_knorm, assign_key);
    }

    count_kernel<<<(B_ * M_) / 256, 256, 0, stream>>>(assign_key, count);
    scan_kernel<<<B_, 1024, 0, stream>>>(count, offset);
    fill_kernel<<<(B_ * M_) / 256, 256, 0, stream>>>(assign_key, offset, count, list);

    merge_kernel<<<B_ * K_, 256, 0, stream>>>(tokens, scores, kept_idx, kept_sc,
                                              dropped_idx, offset, list, out_tok);
}

// Round 4
// 932.222 us; speedup vs baseline: 2.5343x; 1.0182x over previous
//
#include <hip/hip_runtime.h>
#include <hip/hip_bf16.h>

#define B_ 16
#define N_ 4096
#define D_ 1024
#define K_ 1024
#define M_ 3072

typedef unsigned short u16;
typedef unsigned int u32;
typedef __attribute__((ext_vector_type(8))) short bf16x8;
typedef __attribute__((ext_vector_type(4))) float f32x4;

// round-to-nearest-even fp32 -> bf16
__device__ inline u16 bf16_rn(float x) {
    unsigned u = __float_as_uint(x);
    u += 0x7fffu + ((u >> 16) & 1u);
    return (u16)(u >> 16);
}
__device__ inline void bf16_split(float x, u16& h, u16& l) {
    h = bf16_rn(x);
    const float hf = __uint_as_float(((unsigned)h) << 16);
    l = bf16_rn(x - hf);
}

// ---------------------------------------------------------------------------
// Kernel 1: per-batch top-K selection (JAX tie semantics), kept ascending,
// dropped ascending. One block per batch; bitonic sort of u64 keys in LDS.
// Also writes rank[b][e] = kept ? kpos : K+q (drives the fused convert).
// ---------------------------------------------------------------------------
__global__ __launch_bounds__(1024)
void topk_kernel(const float* __restrict__ scores,
                 float* __restrict__ out_idx_f, float* __restrict__ out_sc,
                 int* __restrict__ kept_idx, int* __restrict__ dropped_idx,
                 float* __restrict__ kept_sc, u32* __restrict__ rank,
                 unsigned long long* __restrict__ assign_key)
{
    const int b = blockIdx.x;
    const int tid = threadIdx.x;
    __shared__ unsigned long long keys[N_];
    __shared__ unsigned wsum[16];

    for (int m = tid; m < M_; m += 1024) assign_key[b * M_ + m] = 0ull;

    for (int i = tid; i < N_; i += 1024) {
        float s = scores[b * N_ + i];
        unsigned sb = __float_as_uint(s);
        sb = (sb & 0x80000000u) ? ~sb : (sb | 0x80000000u);
        keys[i] = ((unsigned long long)sb << 32) | (unsigned)(N_ - 1 - i);
    }
    __syncthreads();

    for (unsigned k = 2; k <= (unsigned)N_; k <<= 1) {
        for (unsigned j = k >> 1; j > 0; j >>= 1) {
            for (unsigned i = tid; i < (unsigned)N_; i += 1024) {
                unsigned ixj = i ^ j;
                if (ixj > i) {
                    unsigned long long a = keys[i], c = keys[ixj];
                    bool up = ((i & k) == 0);
                    if ((a > c) == up) { keys[i] = c; keys[ixj] = a; }
                }
            }
            __syncthreads();
        }
    }

    const unsigned long long thr = keys[N_ - K_];
    const int lane = tid & 63, w = tid >> 6;
    unsigned carry = 0;

    for (int r = 0; r < 4; ++r) {
        const int e = r * 1024 + tid;
        const float s = scores[b * N_ + e];
        unsigned sb = __float_as_uint(s);
        sb = (sb & 0x80000000u) ? ~sb : (sb | 0x80000000u);
        const unsigned long long key =
            ((unsigned long long)sb << 32) | (unsigned)(N_ - 1 - e);
        const bool kept = (key >= thr);

        const unsigned long long mb = __ballot(kept);
        const unsigned lanePre = (unsigned)__popcll(mb & ((1ull << lane) - 1ull));
        if (lane == 0) wsum[w] = (unsigned)__popcll(mb);
        __syncthreads();
        unsigned waveExcl = 0, roundTot = 0;
        for (int i = 0; i < 16; ++i) {
            unsigned v = wsum[i];
            if (i < w) waveExcl += v;
            roundTot += v;
        }
        const unsigned kpos = carry + waveExcl + lanePre;
        if (kept) {
            out_idx_f[b * K_ + kpos] = (float)e;
            out_sc  [b * K_ + kpos] = s;
            kept_idx[b * K_ + kpos] = e;
            kept_sc [b * K_ + kpos] = fmaxf(s, 0.0f);
            rank    [b * N_ + e]    = kpos;
        } else {
            const unsigned q = (unsigned)e - kpos;
            dropped_idx[b * M_ + q] = e;
            rank       [b * N_ + e] = (u32)K_ + q;
        }
        carry += roundTot;
        __syncthreads();
    }
}

// ---------------------------------------------------------------------------
// Kernel 2 (fused prep+conv): one wave per row of tokens. L2-normalize
// (argmax-invariant for dropped too -> uniform code), bf16 hi/lo split,
// route to khi/klo[kpos] or dhi/dlo[q] via rank. One pass over all B*N rows.
// ---------------------------------------------------------------------------
__global__ __launch_bounds__(256)
void convert_kernel(const float* __restrict__ tokens, const u32* __restrict__ rank,
                    u16* __restrict__ khi, u16* __restrict__ klo,
                    u16* __restrict__ dhi, u16* __restrict__ dlo)
{
    const int w = threadIdx.x >> 6, lane = threadIdx.x & 63;
    const int g = blockIdx.x * 4 + w;          // flat row in [0, B*N)
    const int b = g >> 12;                     // N_ = 4096
    const float* src = tokens + (size_t)g * D_;

    float4 v[4];
    float ss = 0.0f;
#pragma unroll
    for (int j = 0; j < 4; ++j) {
        v[j] = *(const float4*)(src + (lane + j * 64) * 4);
        ss += v[j].x * v[j].x + v[j].y * v[j].y + v[j].z * v[j].z + v[j].w * v[j].w;
    }
#pragma unroll
    for (int sh = 1; sh < 64; sh <<= 1) ss += __shfl_xor(ss, sh, 64);
    const float inv = 1.0f / fmaxf(sqrtf(ss), 1e-12f);

    const u32 r = rank[g];
    u16 *hp, *lp;
    if (r < (u32)K_) {
        hp = khi + ((size_t)b * K_ + r) * D_;
        lp = klo + ((size_t)b * K_ + r) * D_;
    } else {
        hp = dhi + ((size_t)b * M_ + (r - K_)) * D_;
        lp = dlo + ((size_t)b * M_ + (r - K_)) * D_;
    }
#pragma unroll
    for (int j = 0; j < 4; ++j) {
        ushort4 h, l;
        bf16_split(v[j].x * inv, h.x, l.x);
        bf16_split(v[j].y * inv, h.y, l.y);
        bf16_split(v[j].z * inv, h.z, l.z);
        bf16_split(v[j].w * inv, h.w, l.w);
        *(ushort4*)(hp + 4 * (lane + 64 * j)) = h;
        *(ushort4*)(lp + 4 * (lane + 64 * j)) = l;
    }
}

// ---------------------------------------------------------------------------
// Kernel 3 (MFMA): sim = d_norm . k_norm^T via 3-pass split-bf16.
// Tile 128x128, BK=32, fragment-order LDS staged by global_load_lds w=16.
// XCD swizzle: linear = z*192 + j*8 + c, XCD ~ linear%8 -> each XCD owns a
// 3-mt band (A-tiles pinned in its L2) and walks all nt within it.
// Fused row-argmax via packed u64 atomicMax (max sim, tie -> min n).
// ---------------------------------------------------------------------------
__global__ __launch_bounds__(256)
void sim_mfma_kernel(const u16* __restrict__ dhi, const u16* __restrict__ dlo,
                     const u16* __restrict__ khi, const u16* __restrict__ klo,
                     unsigned long long* __restrict__ assign_key)
{
    const int c = blockIdx.x;                  // [0,8)  fast dim -> XCD id
    const int j = blockIdx.y;                  // [0,24)
    const int b = blockIdx.z;
    const int mt = c * 3 + (j % 3);            // [0,24) dropped tile
    const int nt = j / 3;                      // [0,8)  kept tile
    const int tid = threadIdx.x, w = tid >> 6, lane = tid & 63;
    const int lrow = lane >> 4, lcol = lane & 15;
    __shared__ __align__(16) char smem[32768];   // Ah | Al | Bh | Bl (8KB each)

    const u16* mat;
    if      (w == 0) mat = dhi + ((size_t)b * M_ + mt * 128) * D_;
    else if (w == 1) mat = dlo + ((size_t)b * M_ + mt * 128) * D_;
    else if (w == 2) mat = khi + ((size_t)b * K_ + nt * 128) * D_;
    else             mat = klo + ((size_t)b * K_ + nt * 128) * D_;
    char* ldsbase = smem + w * 8192;

    const int wm = (w & 1) * 64, wn = (w >> 1) * 64;

    f32x4 acc[4][4];
#pragma unroll
    for (int i = 0; i < 4; ++i)
#pragma unroll
        for (int jj = 0; jj < 4; ++jj)
            acc[i][jj] = (f32x4){0.f, 0.f, 0.f, 0.f};

    for (int k0 = 0; k0 < D_; k0 += 32) {
        __syncthreads();
#pragma unroll
        for (int s = 0; s < 8; ++s) {
            const u16* gp = mat + (size_t)(s * 16 + lcol) * D_ + k0 + lrow * 8;
            __builtin_amdgcn_global_load_lds(
                (const __attribute__((address_space(1))) void*)gp,
                (__attribute__((address_space(3))) void*)(ldsbase + s * 1024),
                16, 0, 0);
        }
        __syncthreads();

        bf16x8 ah[4], al[4], bh[4], bl[4];
#pragma unroll
        for (int i = 0; i < 4; ++i) {
            ah[i] = *(const bf16x8*)(smem +     0 + (wm / 16 + i) * 1024 + lane * 16);
            al[i] = *(const bf16x8*)(smem +  8192 + (wm / 16 + i) * 1024 + lane * 16);
            bh[i] = *(const bf16x8*)(smem + 16384 + (wn / 16 + i) * 1024 + lane * 16);
            bl[i] = *(const bf16x8*)(smem + 24576 + (wn / 16 + i) * 1024 + lane * 16);
        }
#pragma unroll
        for (int i = 0; i < 4; ++i)
#pragma unroll
            for (int jj = 0; jj < 4; ++jj) {
                acc[i][jj] = __builtin_amdgcn_mfma_f32_16x16x32_bf16(al[i], bh[jj], acc[i][jj], 0, 0, 0);
                acc[i][jj] = __builtin_amdgcn_mfma_f32_16x16x32_bf16(ah[i], bl[jj], acc[i][jj], 0, 0, 0);
                acc[i][jj] = __builtin_amdgcn_mfma_f32_16x16x32_bf16(ah[i], bh[jj], acc[i][jj], 0, 0, 0);
            }
    }

    // epilogue: per-row argmax.  C layout: col = lane&15, row = (lane>>4)*4+reg.
#pragma unroll
    for (int i = 0; i < 4; ++i) {
#pragma unroll
        for (int r = 0; r < 4; ++r) {
            float bv = acc[i][0][r];
            int   bn = wn + lcol;
#pragma unroll
            for (int jj = 1; jj < 4; ++jj) {
                const float v = acc[i][jj][r];
                if (v > bv) { bv = v; bn = wn + jj * 16 + lcol; }
            }
            unsigned u = __float_as_uint(bv);
            u = (u & 0x80000000u) ? ~u : (u | 0x80000000u);
            unsigned long long key = ((unsigned long long)u << 32)
                                   | (unsigned long long)(0xFFFFFFFFu - (unsigned)(nt * 128 + bn));
#pragma unroll
            for (int sh = 1; sh < 16; sh <<= 1) {
                const unsigned long long o = __shfl_xor(key, sh, 64);
                if (o > key) key = o;
            }
            if (lcol == 0) {
                const int m = mt * 128 + wm + i * 16 + lrow * 4 + r;
                atomicMax(&assign_key[b * M_ + m], key);
            }
        }
    }
}

// ---------------------------------------------------------------------------
// Kernel 4 (fused count+scan+fill): one block per batch. LDS histogram of
// assignments, exclusive scan, then bucket-fill per-slot lists via LDS
// cursors. Order within a slot is arbitrary (fp32 sum noise only).
// ---------------------------------------------------------------------------
__global__ __launch_bounds__(1024)
void binning_kernel(const unsigned long long* __restrict__ assign_key,
                    u32* __restrict__ offset, u32* __restrict__ list)
{
    const int b = blockIdx.x;
    const int t = threadIdx.x;
    __shared__ u32 cnt[1024];
    __shared__ u32 sb[1024];

    cnt[t] = 0u;
    __syncthreads();
    int kk[3];
#pragma unroll
    for (int i = 0; i < 3; ++i) {
        const int m = t + i * 1024;
        kk[i] = (int)(0xFFFFFFFFu - (unsigned)(assign_key[b * M_ + m] & 0xFFFFFFFFull));
        atomicAdd(&cnt[kk[i]], 1u);
    }
    __syncthreads();
    const u32 c = cnt[t];
    sb[t] = c;
    __syncthreads();
    for (int d = 1; d < 1024; d <<= 1) {
        const u32 v = (t >= d) ? sb[t - d] : 0u;
        __syncthreads();
        sb[t] += v;
        __syncthreads();
    }
    const u32 excl = sb[t] - c;
    offset[b * K_ + t] = excl;
    cnt[t] = excl;                      // reuse as cursor
    __syncthreads();
#pragma unroll
    for (int i = 0; i < 3; ++i) {
        const int m = t + i * 1024;
        const u32 pos = atomicAdd(&cnt[kk[i]], 1u);
        list[b * M_ + pos] = (u32)(b * M_ + m);
    }
}

// ---------------------------------------------------------------------------
// Kernel 5: gather-merge. One block per kept slot: out =
// (kept*ksc + sum s*dropped) / max(ksc + sum s, EPS). No atomics.
// ---------------------------------------------------------------------------
__global__ __launch_bounds__(256)
void merge_kernel(const float* __restrict__ tokens, const float* __restrict__ scores,
                  const int* __restrict__ kept_idx, const float* __restrict__ kept_sc,
                  const int* __restrict__ dropped_idx,
                  const u32* __restrict__ offset, const u32* __restrict__ list,
                  float* __restrict__ out_tok)
{
    const int r = blockIdx.x;                   // [0, B*K)
    const int b = r >> 10;
    const int t = threadIdx.x;
    const u32 o = offset[r];
    const u32 e = ((r & (K_ - 1)) == K_ - 1) ? (u32)M_ : offset[r + 1];
    const float ksc = kept_sc[r];
    const int kIdx = kept_idx[r];

    float4 acc = *(const float4*)(tokens + ((size_t)b * N_ + kIdx) * D_ + t * 4);
    acc.x *= ksc; acc.y *= ksc; acc.z *= ksc; acc.w *= ksc;
    float ssum = 0.0f;

    for (u32 i = o; i < e; ++i) {
        const int g = (int)list[b * M_ + i];
        const int dIdx = dropped_idx[g];
        const float s = fmaxf(scores[b * N_ + dIdx], 0.0f);
        const float4 v = *(const float4*)(tokens + ((size_t)b * N_ + dIdx) * D_ + t * 4);
        acc.x += s * v.x; acc.y += s * v.y; acc.z += s * v.z; acc.w += s * v.w;
        ssum += s;
    }

    const float inv = 1.0f / fmaxf(ksc + ssum, 1e-6f);
    acc.x *= inv; acc.y *= inv; acc.z *= inv; acc.w *= inv;
    *(float4*)(out_tok + (size_t)r * D_ + t * 4) = acc;
}

// ---------------------------------------------------------------------------
extern "C" void kernel_launch(void* const* d_in, const int* in_sizes, int n_in,
                              void* d_out, int out_size, void* d_ws, size_t ws_size,
                              hipStream_t stream)
{
    const float* tokens = (const float*)d_in[0];
    const float* scores = (const float*)d_in[1];

    float* out = (float*)d_out;
    float* out_tok = out;                              // [B,K,D]
    float* out_idx = out + (size_t)B_ * K_ * D_;       // [B,K]
    float* out_sc  = out_idx + (size_t)B_ * K_;        // [B,K]

    char* ws = (char*)d_ws;
    int*   kept_idx    = (int*)(ws);                   //       0,  64 KB
    int*   dropped_idx = (int*)(ws + 65536);           //   64 KB, 192 KB
    float* kept_sc     = (float*)(ws + 262144);        //  256 KB,  64 KB
    u32*   rank        = (u32*)(ws + 327680);          //  320 KB, 256 KB
    unsigned long long* assign_key =
        (unsigned long long*)(ws + 589824);            //  576 KB, 384 KB
    u32*   offset      = (u32*)(ws + 983040);          //  960 KB,  64 KB
    u32*   list        = (u32*)(ws + 1048576);         // 1024 KB, 192 KB

    const size_t splitBase = 1310720;                  // 1.25 MB
    const size_t kSplit = (size_t)B_ * K_ * D_ * 2;    // 32 MB each
    const size_t dSplit = (size_t)B_ * M_ * D_ * 2;    // 96 MB each
    u16* khi = (u16*)(ws + splitBase);
    u16* klo = (u16*)((char*)khi + kSplit);
    u16* dhi = (u16*)((char*)klo + kSplit);
    u16* dlo = (u16*)((char*)dhi + dSplit);

    topk_kernel<<<B_, 1024, 0, stream>>>(scores, out_idx, out_sc,
                                         kept_idx, dropped_idx, kept_sc, rank,
                                         assign_key);

    convert_kernel<<<(B_ * N_) / 4, 256, 0, stream>>>(tokens, rank,
                                                      khi, klo, dhi, dlo);

    dim3 g3(8, 24, B_);   // x = XCD band id (fast), y = 3*mt-in-band x nt
    sim_mfma_kernel<<<g3, 256, 0, stream>>>(dhi, dlo, khi, klo, assign_key);

    binning_kernel<<<B_, 1024, 0, stream>>>(assign_key, offset, list);

    merge_kernel<<<B_ * K_, 256, 0, stream>>>(tokens, scores, kept_idx, kept_sc,
                                              dropped_idx, offset, list, out_tok);
}

// Round 5
// 882.797 us; speedup vs baseline: 2.6762x; 1.0560x over previous
//
#include <hip/hip_runtime.h>
#include <hip/hip_bf16.h>

#define B_ 16
#define N_ 4096
#define D_ 1024
#define K_ 1024
#define M_ 3072

typedef unsigned short u16;
typedef unsigned int u32;
typedef unsigned long long u64;
typedef __attribute__((ext_vector_type(8))) short bf16x8;
typedef __attribute__((ext_vector_type(4))) float f32x4;

// round-to-nearest-even fp32 -> bf16
__device__ inline u16 bf16_rn(float x) {
    unsigned u = __float_as_uint(x);
    u += 0x7fffu + ((u >> 16) & 1u);
    return (u16)(u >> 16);
}
__device__ inline void bf16_split(float x, u16& h, u16& l) {
    h = bf16_rn(x);
    const float hf = __uint_as_float(((unsigned)h) << 16);
    l = bf16_rn(x - hf);
}

// ---------------------------------------------------------------------------
// Kernel 1: per-batch top-K via u64 radix select (replaces bitonic sort).
// key = (monotone(score_bits) << 32) | (N-1-i): unique keys, JAX tie
// semantics (equal score -> lower index wins). Levels of 11 bits from the
// top; LDS histogram + suffix scan finds the boundary bin; early-exit when
// boundary-bin count == remaining need (thr = prefix << remaining_bits).
// Then ballot-compaction: kept ascending, dropped ascending; writes rank.
// ---------------------------------------------------------------------------
__global__ __launch_bounds__(1024)
void topk_kernel(const float* __restrict__ scores,
                 float* __restrict__ out_idx_f, float* __restrict__ out_sc,
                 int* __restrict__ kept_idx, int* __restrict__ dropped_idx,
                 float* __restrict__ kept_sc, u32* __restrict__ rank,
                 u64* __restrict__ assign_key)
{
    const int b = blockIdx.x;
    const int tid = threadIdx.x;
    __shared__ u32 hist[2048];
    __shared__ u32 wsum[16];
    __shared__ u64 s_thr;
    __shared__ u32 s_bb, s_need;

    for (int m = tid; m < M_; m += 1024) assign_key[b * M_ + m] = 0ull;

    // build keys (4 per thread, element e = r*1024 + tid)
    float sval[4];
    u64 key[4];
#pragma unroll
    for (int r = 0; r < 4; ++r) {
        const int e = r * 1024 + tid;
        const float s = scores[b * N_ + e];
        sval[r] = s;
        unsigned sb = __float_as_uint(s);
        sb = (sb & 0x80000000u) ? ~sb : (sb | 0x80000000u);
        key[r] = ((u64)sb << 32) | (unsigned)(N_ - 1 - e);
    }

    // radix select: widths 11,11,11,11,11,9 (MSB first)
    u64 prefix = 0;
    u32 need = K_;
    int consumed = 0;
    bool done = false;

#pragma unroll
    for (int lvl = 0; lvl < 6; ++lvl) {
        if (!done) {
            const int w = (lvl < 5) ? 11 : 9;
            const int sh = 64 - consumed - w;

            hist[tid] = 0u; hist[tid + 1024] = 0u;
            __syncthreads();
#pragma unroll
            for (int r = 0; r < 4; ++r) {
                const bool cand = (lvl == 0) || ((key[r] >> (64 - consumed)) == prefix);
                if (cand) atomicAdd(&hist[(u32)(key[r] >> sh) & ((1u << w) - 1u)], 1u);
            }
            __syncthreads();
            // suffix scan: hist[i] := sum_{j>=i} hist[j]
            for (int d = 1; d < 2048; d <<= 1) {
                const u32 v0 = (tid + d < 2048) ? hist[tid + d] : 0u;
                const u32 v1 = (tid + 1024 + d < 2048) ? hist[tid + 1024 + d] : 0u;
                __syncthreads();
                hist[tid] += v0; hist[tid + 1024] += v1;
                __syncthreads();
            }
            // boundary bin: max bin with S(bin) >= need
#pragma unroll
            for (int h = 0; h < 2; ++h) {
                const int i = tid + h * 1024;
                if (hist[i] >= need && (i == 2047 || hist[i + 1] < need)) s_bb = (u32)i;
            }
            __syncthreads();
            const u32 bb = s_bb;
            const u32 c_hi = (bb < 2047u) ? hist[bb + 1] : 0u;
            const u32 cnt_bb = hist[bb] - c_hi;
            __syncthreads();           // hist reuse next level

            prefix = (prefix << w) | bb;
            consumed += w;
            need -= c_hi;
            if (cnt_bb == need || consumed == 64) {
                if (tid == 0) s_thr = prefix << (64 - consumed);
                done = true;
            }
        }
    }
    __syncthreads();
    const u64 thr = s_thr;

    // ballot compaction (kept ascending, dropped ascending)
    const int lane = tid & 63, wv = tid >> 6;
    unsigned carry = 0;
#pragma unroll
    for (int r = 0; r < 4; ++r) {
        const int e = r * 1024 + tid;
        const bool kept = (key[r] >= thr);

        const u64 mb = __ballot(kept);
        const unsigned lanePre = (unsigned)__popcll(mb & ((1ull << lane) - 1ull));
        if (lane == 0) wsum[wv] = (unsigned)__popcll(mb);
        __syncthreads();
        unsigned waveExcl = 0, roundTot = 0;
        for (int i = 0; i < 16; ++i) {
            const unsigned v = wsum[i];
            if (i < wv) waveExcl += v;
            roundTot += v;
        }
        const unsigned kpos = carry + waveExcl + lanePre;
        if (kept) {
            out_idx_f[b * K_ + kpos] = (float)e;
            out_sc  [b * K_ + kpos] = sval[r];
            kept_idx[b * K_ + kpos] = e;
            kept_sc [b * K_ + kpos] = fmaxf(sval[r], 0.0f);
            rank    [b * N_ + e]    = kpos;
        } else {
            const unsigned q = (unsigned)e - kpos;
            dropped_idx[b * M_ + q] = e;
            rank       [b * N_ + e] = (u32)K_ + q;
        }
        carry += roundTot;
        __syncthreads();
    }
}

// ---------------------------------------------------------------------------
// Kernel 2 (fused prep+conv): one wave per row of tokens. L2-normalize
// (argmax-invariant for dropped too -> uniform code), bf16 hi/lo split,
// route to khi/klo[kpos] or dhi/dlo[q] via rank. One pass over all B*N rows.
// ---------------------------------------------------------------------------
__global__ __launch_bounds__(256)
void convert_kernel(const float* __restrict__ tokens, const u32* __restrict__ rank,
                    u16* __restrict__ khi, u16* __restrict__ klo,
                    u16* __restrict__ dhi, u16* __restrict__ dlo)
{
    const int w = threadIdx.x >> 6, lane = threadIdx.x & 63;
    const int g = blockIdx.x * 4 + w;          // flat row in [0, B*N)
    const int b = g >> 12;                     // N_ = 4096
    const float* src = tokens + (size_t)g * D_;

    float4 v[4];
    float ss = 0.0f;
#pragma unroll
    for (int j = 0; j < 4; ++j) {
        v[j] = *(const float4*)(src + (lane + j * 64) * 4);
        ss += v[j].x * v[j].x + v[j].y * v[j].y + v[j].z * v[j].z + v[j].w * v[j].w;
    }
#pragma unroll
    for (int sh = 1; sh < 64; sh <<= 1) ss += __shfl_xor(ss, sh, 64);
    const float inv = 1.0f / fmaxf(sqrtf(ss), 1e-12f);

    const u32 r = rank[g];
    u16 *hp, *lp;
    if (r < (u32)K_) {
        hp = khi + ((size_t)b * K_ + r) * D_;
        lp = klo + ((size_t)b * K_ + r) * D_;
    } else {
        hp = dhi + ((size_t)b * M_ + (r - K_)) * D_;
        lp = dlo + ((size_t)b * M_ + (r - K_)) * D_;
    }
#pragma unroll
    for (int j = 0; j < 4; ++j) {
        ushort4 h, l;
        bf16_split(v[j].x * inv, h.x, l.x);
        bf16_split(v[j].y * inv, h.y, l.y);
        bf16_split(v[j].z * inv, h.z, l.z);
        bf16_split(v[j].w * inv, h.w, l.w);
        *(ushort4*)(hp + 4 * (lane + 64 * j)) = h;
        *(ushort4*)(lp + 4 * (lane + 64 * j)) = l;
    }
}

// ---------------------------------------------------------------------------
// Kernel 3 (MFMA): sim = d_norm . k_norm^T via 3-pass split-bf16.
// Tile 128x128, BK=32, fragment-order LDS staged by global_load_lds w=16.
// XCD swizzle: x = XCD band (fast), each XCD owns a 3-mt band x all nt.
// Fused row-argmax via packed u64 atomicMax (max sim, tie -> min n).
// ---------------------------------------------------------------------------
__global__ __launch_bounds__(256)
void sim_mfma_kernel(const u16* __restrict__ dhi, const u16* __restrict__ dlo,
                     const u16* __restrict__ khi, const u16* __restrict__ klo,
                     u64* __restrict__ assign_key)
{
    const int c = blockIdx.x;                  // [0,8)  fast dim -> XCD id
    const int j = blockIdx.y;                  // [0,24)
    const int b = blockIdx.z;
    const int mt = c * 3 + (j % 3);            // [0,24) dropped tile
    const int nt = j / 3;                      // [0,8)  kept tile
    const int tid = threadIdx.x, w = tid >> 6, lane = tid & 63;
    const int lrow = lane >> 4, lcol = lane & 15;
    __shared__ __align__(16) char smem[32768];   // Ah | Al | Bh | Bl (8KB each)

    const u16* mat;
    if      (w == 0) mat = dhi + ((size_t)b * M_ + mt * 128) * D_;
    else if (w == 1) mat = dlo + ((size_t)b * M_ + mt * 128) * D_;
    else if (w == 2) mat = khi + ((size_t)b * K_ + nt * 128) * D_;
    else             mat = klo + ((size_t)b * K_ + nt * 128) * D_;
    char* ldsbase = smem + w * 8192;

    const int wm = (w & 1) * 64, wn = (w >> 1) * 64;

    f32x4 acc[4][4];
#pragma unroll
    for (int i = 0; i < 4; ++i)
#pragma unroll
        for (int jj = 0; jj < 4; ++jj)
            acc[i][jj] = (f32x4){0.f, 0.f, 0.f, 0.f};

    for (int k0 = 0; k0 < D_; k0 += 32) {
        __syncthreads();
#pragma unroll
        for (int s = 0; s < 8; ++s) {
            const u16* gp = mat + (size_t)(s * 16 + lcol) * D_ + k0 + lrow * 8;
            __builtin_amdgcn_global_load_lds(
                (const __attribute__((address_space(1))) void*)gp,
                (__attribute__((address_space(3))) void*)(ldsbase + s * 1024),
                16, 0, 0);
        }
        __syncthreads();

        bf16x8 ah[4], al[4], bh[4], bl[4];
#pragma unroll
        for (int i = 0; i < 4; ++i) {
            ah[i] = *(const bf16x8*)(smem +     0 + (wm / 16 + i) * 1024 + lane * 16);
            al[i] = *(const bf16x8*)(smem +  8192 + (wm / 16 + i) * 1024 + lane * 16);
            bh[i] = *(const bf16x8*)(smem + 16384 + (wn / 16 + i) * 1024 + lane * 16);
            bl[i] = *(const bf16x8*)(smem + 24576 + (wn / 16 + i) * 1024 + lane * 16);
        }
#pragma unroll
        for (int i = 0; i < 4; ++i)
#pragma unroll
            for (int jj = 0; jj < 4; ++jj) {
                acc[i][jj] = __builtin_amdgcn_mfma_f32_16x16x32_bf16(al[i], bh[jj], acc[i][jj], 0, 0, 0);
                acc[i][jj] = __builtin_amdgcn_mfma_f32_16x16x32_bf16(ah[i], bl[jj], acc[i][jj], 0, 0, 0);
                acc[i][jj] = __builtin_amdgcn_mfma_f32_16x16x32_bf16(ah[i], bh[jj], acc[i][jj], 0, 0, 0);
            }
    }

    // epilogue: per-row argmax.  C layout: col = lane&15, row = (lane>>4)*4+reg.
#pragma unroll
    for (int i = 0; i < 4; ++i) {
#pragma unroll
        for (int r = 0; r < 4; ++r) {
            float bv = acc[i][0][r];
            int   bn = wn + lcol;
#pragma unroll
            for (int jj = 1; jj < 4; ++jj) {
                const float v = acc[i][jj][r];
                if (v > bv) { bv = v; bn = wn + jj * 16 + lcol; }
            }
            unsigned u = __float_as_uint(bv);
            u = (u & 0x80000000u) ? ~u : (u | 0x80000000u);
            u64 kkey = ((u64)u << 32)
                     | (u64)(0xFFFFFFFFu - (unsigned)(nt * 128 + bn));
#pragma unroll
            for (int sh = 1; sh < 16; sh <<= 1) {
                const u64 o = __shfl_xor(kkey, sh, 64);
                if (o > kkey) kkey = o;
            }
            if (lcol == 0) {
                const int m = mt * 128 + wm + i * 16 + lrow * 4 + r;
                atomicMax(&assign_key[b * M_ + m], kkey);
            }
        }
    }
}

// ---------------------------------------------------------------------------
// Kernel 4 (fused count+scan+fill): one block per batch. LDS histogram of
// assignments, exclusive scan, then bucket-fill per-slot lists via LDS
// cursors. Order within a slot is arbitrary (fp32 sum noise only).
// ---------------------------------------------------------------------------
__global__ __launch_bounds__(1024)
void binning_kernel(const u64* __restrict__ assign_key,
                    u32* __restrict__ offset, u32* __restrict__ list)
{
    const int b = blockIdx.x;
    const int t = threadIdx.x;
    __shared__ u32 cnt[1024];
    __shared__ u32 sb[1024];

    cnt[t] = 0u;
    __syncthreads();
    int kk[3];
#pragma unroll
    for (int i = 0; i < 3; ++i) {
        const int m = t + i * 1024;
        kk[i] = (int)(0xFFFFFFFFu - (unsigned)(assign_key[b * M_ + m] & 0xFFFFFFFFull));
        atomicAdd(&cnt[kk[i]], 1u);
    }
    __syncthreads();
    const u32 c = cnt[t];
    sb[t] = c;
    __syncthreads();
    for (int d = 1; d < 1024; d <<= 1) {
        const u32 v = (t >= d) ? sb[t - d] : 0u;
        __syncthreads();
        sb[t] += v;
        __syncthreads();
    }
    const u32 excl = sb[t] - c;
    offset[b * K_ + t] = excl;
    cnt[t] = excl;                      // reuse as cursor
    __syncthreads();
#pragma unroll
    for (int i = 0; i < 3; ++i) {
        const int m = t + i * 1024;
        const u32 pos = atomicAdd(&cnt[kk[i]], 1u);
        list[b * M_ + pos] = (u32)(b * M_ + m);
    }
}

// ---------------------------------------------------------------------------
// Kernel 5: gather-merge. One block per kept slot: out =
// (kept*ksc + sum s*dropped) / max(ksc + sum s, EPS). No atomics.
// ---------------------------------------------------------------------------
__global__ __launch_bounds__(256)
void merge_kernel(const float* __restrict__ tokens, const float* __restrict__ scores,
                  const int* __restrict__ kept_idx, const float* __restrict__ kept_sc,
                  const int* __restrict__ dropped_idx,
                  const u32* __restrict__ offset, const u32* __restrict__ list,
                  float* __restrict__ out_tok)
{
    const int r = blockIdx.x;                   // [0, B*K)
    const int b = r >> 10;
    const int t = threadIdx.x;
    const u32 o = offset[r];
    const u32 e = ((r & (K_ - 1)) == K_ - 1) ? (u32)M_ : offset[r + 1];
    const float ksc = kept_sc[r];
    const int kIdx = kept_idx[r];

    float4 acc = *(const float4*)(tokens + ((size_t)b * N_ + kIdx) * D_ + t * 4);
    acc.x *= ksc; acc.y *= ksc; acc.z *= ksc; acc.w *= ksc;
    float ssum = 0.0f;

    for (u32 i = o; i < e; ++i) {
        const int g = (int)list[b * M_ + i];
        const int dIdx = dropped_idx[g];
        const float s = fmaxf(scores[b * N_ + dIdx], 0.0f);
        const float4 v = *(const float4*)(tokens + ((size_t)b * N_ + dIdx) * D_ + t * 4);
        acc.x += s * v.x; acc.y += s * v.y; acc.z += s * v.z; acc.w += s * v.w;
        ssum += s;
    }

    const float inv = 1.0f / fmaxf(ksc + ssum, 1e-6f);
    acc.x *= inv; acc.y *= inv; acc.z *= inv; acc.w *= inv;
    *(float4*)(out_tok + (size_t)r * D_ + t * 4) = acc;
}

// ---------------------------------------------------------------------------
extern "C" void kernel_launch(void* const* d_in, const int* in_sizes, int n_in,
                              void* d_out, int out_size, void* d_ws, size_t ws_size,
                              hipStream_t stream)
{
    const float* tokens = (const float*)d_in[0];
    const float* scores = (const float*)d_in[1];

    float* out = (float*)d_out;
    float* out_tok = out;                              // [B,K,D]
    float* out_idx = out + (size_t)B_ * K_ * D_;       // [B,K]
    float* out_sc  = out_idx + (size_t)B_ * K_;        // [B,K]

    char* ws = (char*)d_ws;
    int*   kept_idx    = (int*)(ws);                   //       0,  64 KB
    int*   dropped_idx = (int*)(ws + 65536);           //   64 KB, 192 KB
    float* kept_sc     = (float*)(ws + 262144);        //  256 KB,  64 KB
    u32*   rank        = (u32*)(ws + 327680);          //  320 KB, 256 KB
    u64*   assign_key  = (u64*)(ws + 589824);          //  576 KB, 384 KB
    u32*   offset      = (u32*)(ws + 983040);          //  960 KB,  64 KB
    u32*   list        = (u32*)(ws + 1048576);         // 1024 KB, 192 KB

    const size_t splitBase = 1310720;                  // 1.25 MB
    const size_t kSplit = (size_t)B_ * K_ * D_ * 2;    // 32 MB each
    const size_t dSplit = (size_t)B_ * M_ * D_ * 2;    // 96 MB each
    u16* khi = (u16*)(ws + splitBase);
    u16* klo = (u16*)((char*)khi + kSplit);
    u16* dhi = (u16*)((char*)klo + kSplit);
    u16* dlo = (u16*)((char*)dhi + dSplit);

    topk_kernel<<<B_, 1024, 0, stream>>>(scores, out_idx, out_sc,
                                         kept_idx, dropped_idx, kept_sc, rank,
                                         assign_key);

    convert_kernel<<<(B_ * N_) / 4, 256, 0, stream>>>(tokens, rank,
                                                      khi, klo, dhi, dlo);

    dim3 g3(8, 24, B_);   // x = XCD band id (fast), y = 3*mt-in-band x nt
    sim_mfma_kernel<<<g3, 256, 0, stream>>>(dhi, dlo, khi, klo, assign_key);

    binning_kernel<<<B_, 1024, 0, stream>>>(assign_key, offset, list);

    merge_kernel<<<B_ * K_, 256, 0, stream>>>(tokens, scores, kept_idx, kept_sc,
                                              dropped_idx, offset, list, out_tok);
}